// Round 6
// baseline (345.639 us; speedup 1.0000x reference)
//
#include <hip/hip_runtime.h>
#include <math.h>

#define N_NODES 20000
#define N_EDGES 320000
#define ETOT (N_EDGES + N_NODES)
#define HID 16
#define OMEGA 100.0f
#define BETA 0.2f

typedef float  f32x4 __attribute__((ext_vector_type(4)));
typedef short  s16x8 __attribute__((ext_vector_type(8)));

__device__ __forceinline__ float sinrev(float x) { return __builtin_amdgcn_sinf(x); }
__device__ __forceinline__ float fract_f(float x) { return __builtin_amdgcn_fractf(x); }

__device__ __forceinline__ float selu_f(float v) {
    const float a  = 1.6732632423543772f;
    const float sc = 1.0507009873554805f;
    return sc * (v > 0.f ? v : a * expm1f(v));
}

__device__ __forceinline__ f32x4 mfma16(s16x8 a, s16x8 b, f32x4 c) {
    return __builtin_amdgcn_mfma_f32_16x16x32_bf16(a, b, c, 0, 0, 0);
}

// split 4 f32 into bf16 hi/lo B-fragments (k = 8q+{0..3}, rest zero)
__device__ __forceinline__ void pack_hi_lo(float x0, float x1, float x2, float x3,
                                           s16x8& hi, s16x8& lo) {
    union { s16x8 s; unsigned u[4]; } H, L;
    unsigned a0 = __float_as_uint(x0), a1 = __float_as_uint(x1);
    unsigned a2 = __float_as_uint(x2), a3 = __float_as_uint(x3);
    H.u[0] = (a1 & 0xFFFF0000u) | (a0 >> 16);
    H.u[1] = (a3 & 0xFFFF0000u) | (a2 >> 16);
    H.u[2] = 0u; H.u[3] = 0u;
    float r0 = x0 - __uint_as_float(a0 & 0xFFFF0000u);
    float r1 = x1 - __uint_as_float(a1 & 0xFFFF0000u);
    float r2 = x2 - __uint_as_float(a2 & 0xFFFF0000u);
    float r3 = x3 - __uint_as_float(a3 & 0xFFFF0000u);
    unsigned c0 = __float_as_uint(r0), c1 = __float_as_uint(r1);
    unsigned c2 = __float_as_uint(r2), c3 = __float_as_uint(r3);
    L.u[0] = (c1 & 0xFFFF0000u) | (c0 >> 16);
    L.u[1] = (c3 & 0xFFFF0000u) | (c2 >> 16);
    L.u[2] = 0u; L.u[3] = 0u;
    hi = H.s; lo = L.s;
}

// ---------------------------------------------------------------- per-conv prep
// P layout (floats): [0:64) w0 rows {wx,wy,wz,wc} prescaled; [64:80) s*b0;
// [80:96) s*b1; [96:112) s*b2; [128:384) w1 hi frags (uint4[64]);
// [384:640) w1 lo; [640:896) w2 hi; [896:1152) w2 lo; [1152:1408) h2v[OUT*16]
template<int OUT>
__global__ __launch_bounds__(256) void prep_conv_kernel(
    const float* __restrict__ w0, const float* __restrict__ b0,
    const float* __restrict__ w1, const float* __restrict__ b1,
    const float* __restrict__ w2, const float* __restrict__ b2,
    float* __restrict__ P)
{
    __shared__ float w0s[64], b0s[16], sw1s[256], b1s[16], sw2s[256], b2s[16];
    int t = threadIdx.x;
    const float s = OMEGA * 0.15915494309189535f;  // omega/(2*pi)
    if (t < 64)  w0s[t] = s * w0[t];
    if (t < 16)  b0s[t] = s * b0[t];
    sw1s[t] = s * w1[t];
    sw2s[t] = s * w2[t];
    if (t >= 32 && t < 48) b1s[t - 32] = s * b1[t - 32];
    if (t >= 48 && t < 64) b2s[t - 48] = s * b2[t - 48];
    __syncthreads();

    if (t < 64)  P[t] = w0s[t];
    else if (t < 80)  P[t] = b0s[t - 64];
    else if (t < 96)  P[t] = b1s[t - 80];
    else if (t < 112) P[t] = b2s[t - 96];

    // weight fragments: t<64 -> w1 (lane t); t in [64,128) -> w2 (lane t-64)
    if (t < 128) {
        int lane = t & 63;
        const float* W = (t < 64) ? sw1s : sw2s;
        float* dsthi = P + ((t < 64) ? 128 : 640);
        float* dstlo = P + ((t < 64) ? 384 : 896);
        int g = lane & 15, q = lane >> 4;
        unsigned uh[2], ul[2];
#pragma unroll
        for (int pr = 0; pr < 2; pr++) {
            float x0 = W[g * 16 + 4 * q + 2 * pr];
            float x1 = W[g * 16 + 4 * q + 2 * pr + 1];
            unsigned bb0 = __float_as_uint(x0), bb1 = __float_as_uint(x1);
            uh[pr] = (bb1 & 0xFFFF0000u) | (bb0 >> 16);
            float r0 = x0 - __uint_as_float(bb0 & 0xFFFF0000u);
            float r1 = x1 - __uint_as_float(bb1 & 0xFFFF0000u);
            ul[pr] = (__float_as_uint(r1) & 0xFFFF0000u) | (__float_as_uint(r0) >> 16);
        }
        ((uint4*)dsthi)[lane] = make_uint4(uh[0], uh[1], 0u, 0u);
        ((uint4*)dstlo)[lane] = make_uint4(ul[0], ul[1], 0u, 0u);
    }

    // self-loop h2 chain (feat = 0): depends only on channel o
    if (t < OUT) {
        float oc = (float)t;
        float h0[HID], h1[HID];
#pragma unroll
        for (int h = 0; h < HID; h++)
            h0[h] = sinrev(fract_f(fmaf(oc, w0s[h * 4 + 3], b0s[h])));
#pragma unroll
        for (int g = 0; g < HID; g++) {
            float sa = b1s[g];
#pragma unroll
            for (int h = 0; h < HID; h++) sa += h0[h] * sw1s[g * HID + h];
            h1[g] = sinrev(sa);
        }
#pragma unroll
        for (int g = 0; g < HID; g++) {
            float sa = b2s[g];
#pragma unroll
            for (int h = 0; h < HID; h++) sa += h1[h] * sw2s[g * HID + h];
            P[1152 + t * HID + g] = sinrev(sa);
        }
    }
}

// ---------------------------------------------------------------- edge feats + x copy (fused)
__global__ __launch_bounds__(256) void fused_pre_kernel(
    const int* __restrict__ ei, const float* __restrict__ pos,
    const float* __restrict__ x,
    float4* __restrict__ feat, float* __restrict__ xcat)
{
    if (blockIdx.x < 1250) {
        int e = blockIdx.x * 256 + threadIdx.x;
        if (e >= N_EDGES) return;
        int s = ei[e], d = ei[N_EDGES + e];
        float rx = pos[d * 3 + 0] - pos[s * 3 + 0];
        float ry = pos[d * 3 + 1] - pos[s * 3 + 1];
        float rz = pos[d * 3 + 2] - pos[s * 3 + 2];
        float sq = rx * rx + ry * ry + rz * rz;
        float4 f = make_float4(0.f, 0.f, 0.f, 0.f);
        if (sq > 0.f) {
            float rho = sqrtf(sq);
            float th  = atan2f(ry, rx);
            float ph  = asinf(fminf(fmaxf(rz / rho, -1.f), 1.f));
            const float inv_pi = 0.31830988618379067f;
            f = make_float4(rho, th * inv_pi, ph * inv_pi, 0.f);
        }
        feat[e] = f;
    } else {
        int i = (blockIdx.x - 1250) * 256 + threadIdx.x;
        if (i >= N_NODES * 16) return;
        int n = i >> 4, c = i & 15;
        xcat[n * 32 + c] = x[i];
    }
}

// ---------------------------------------------------------------- per-edge t
template<int IN>
__global__ __launch_bounds__(256) void tbuf_kernel(
    const int* __restrict__ ei, const float* __restrict__ xcat,
    const float* __restrict__ wl, const float* __restrict__ bl,
    float4* __restrict__ tbuf, float* __restrict__ blxb)
{
    int e = blockIdx.x * 256 + threadIdx.x;
    if (e >= ETOT) return;
    int s = (e < N_EDGES) ? ei[e] : e - N_EDGES;

    float t[HID];
#pragma unroll
    for (int h = 0; h < HID; h++) t[h] = 0.f;
    float blx = 0.f;
    const float4* xr = (const float4*)(xcat + s * 32);
#pragma unroll
    for (int i4 = 0; i4 < IN / 4; i4++) {
        float4 xv = xr[i4];
        blx += bl[i4 * 4 + 0] * xv.x + bl[i4 * 4 + 1] * xv.y
             + bl[i4 * 4 + 2] * xv.z + bl[i4 * 4 + 3] * xv.w;
#pragma unroll
        for (int h = 0; h < HID; h++) {
            t[h] += wl[(i4 * 4 + 0) * HID + h] * xv.x
                  + wl[(i4 * 4 + 1) * HID + h] * xv.y
                  + wl[(i4 * 4 + 2) * HID + h] * xv.z
                  + wl[(i4 * 4 + 3) * HID + h] * xv.w;
        }
    }
#pragma unroll
    for (int q = 0; q < 4; q++)
        tbuf[(size_t)e * 4 + q] = make_float4(t[q*4+0], t[q*4+1], t[q*4+2], t[q*4+3]);
    blxb[e] = blx;
}

// ---------------------------------------------------------------- conv via MFMA
// wave handles 16 (edge, channel) items; layers 2/3 = 4x mfma each (bf16 hi/lo exact)
template<int OUT>
__global__ __launch_bounds__(256) void conv_mfma_kernel(
    const int* __restrict__ ei, const float4* __restrict__ feat,
    const float* __restrict__ P,
    const float* __restrict__ tb, const float* __restrict__ blxb,
    float* __restrict__ acc)
{
    constexpr int EPW = 16 / OUT;   // edges per wave: 1 (OUT=16) or 2 (OUT=8)
    int wid  = (blockIdx.x * 256 + threadIdx.x) >> 6;
    int lane = threadIdx.x & 63;
    int item = lane & 15, q = lane >> 4;
    int e = wid * EPW + ((EPW == 2) ? (item >> 3) : 0);
    int o = item & (OUT - 1);
    int d = ei[N_EDGES + e];

    float4 f = feat[e];
    const float4* w0r = (const float4*)P;
    f32x4 b0q = *(const f32x4*)(P + 64 + 4 * q);
    f32x4 c1  = *(const f32x4*)(P + 80 + 4 * q);
    f32x4 c2  = *(const f32x4*)(P + 96 + 4 * q);

    float oc = (float)o;
    // ---- layer 1 (vector): 4 h-values for this (item, quadrant)
    float h0[4];
#pragma unroll
    for (int j = 0; j < 4; j++) {
        float4 w = w0r[4 * q + j];
        float ph = b0q[j] + f.x * w.x + f.y * w.y + f.z * w.z + oc * w.w;
        h0[j] = sinrev(fract_f(ph));
    }
    s16x8 bh, blo;
    pack_hi_lo(h0[0], h0[1], h0[2], h0[3], bh, blo);

    // ---- layer 2 (MFMA)
    union { uint4 v; s16x8 s; } A;
    f32x4 D = c1;
    A.v = ((const uint4*)(P + 128))[lane];  // w1 hi
    D = mfma16(A.s, bh,  D);
    D = mfma16(A.s, blo, D);
    union { uint4 v; s16x8 s; } Al;
    Al.v = ((const uint4*)(P + 384))[lane]; // w1 lo
    D = mfma16(Al.s, bh,  D);
    D = mfma16(Al.s, blo, D);

    float h1[4];
#pragma unroll
    for (int j = 0; j < 4; j++) h1[j] = sinrev(D[j]);
    pack_hi_lo(h1[0], h1[1], h1[2], h1[3], bh, blo);

    // ---- layer 3 (MFMA)
    f32x4 D2 = c2;
    A.v = ((const uint4*)(P + 640))[lane];  // w2 hi
    D2 = mfma16(A.s, bh,  D2);
    D2 = mfma16(A.s, blo, D2);
    Al.v = ((const uint4*)(P + 896))[lane]; // w2 lo
    D2 = mfma16(Al.s, bh,  D2);
    D2 = mfma16(Al.s, blo, D2);

    // ---- dot with t, reduce across quadrants
    f32x4 tv = *(const f32x4*)(tb + (size_t)e * 16 + 4 * q);
    float m = sinrev(D2[0]) * tv[0] + sinrev(D2[1]) * tv[1]
            + sinrev(D2[2]) * tv[2] + sinrev(D2[3]) * tv[3];
    m += __shfl_xor(m, 16);
    m += __shfl_xor(m, 32);
    if (lane < 16)
        atomicAdd(&acc[d * OUT + o], m + blxb[e]);
}

// ---------------------------------------------------------------- finishers (+ self-loop term)
template<int OUT>
__global__ __launch_bounds__(256) void finish_mid_kernel(
    const float* __restrict__ acc, const float* __restrict__ bias,
    const float* __restrict__ h2v,
    const float* __restrict__ tb, const float* __restrict__ blxb,
    float* __restrict__ xcat, int coloff)
{
    int i = blockIdx.x * 256 + threadIdx.x;
    if (i >= N_NODES * OUT) return;
    int n = i / OUT, o = i % OUT;
    const float* tr = tb + (size_t)(N_EDGES + n) * 16;
    float m = blxb[N_EDGES + n];
#pragma unroll
    for (int h = 0; h < HID; h++) m += h2v[o * HID + h] * tr[h];
    xcat[n * 32 + coloff + o] = selu_f(acc[i] + bias[o] + m);
}

__global__ __launch_bounds__(256) void finish_out_kernel(
    const float* __restrict__ acc, const float* __restrict__ bias,
    const float* __restrict__ h2v,
    const float* __restrict__ tb, const float* __restrict__ blxb,
    const float* __restrict__ x, float* __restrict__ out)
{
    int i = blockIdx.x * 256 + threadIdx.x;
    if (i >= N_NODES * 16) return;
    int n = i >> 4, c = i & 15;
    const float* tr = tb + (size_t)(N_EDGES + n) * 16;
    float m = blxb[N_EDGES + n];
#pragma unroll
    for (int h = 0; h < HID; h++) m += h2v[c * HID + h] * tr[h];
    out[i] = x[i] + BETA * selu_f(acc[i] + bias[c] + m);
}

// ---------------------------------------------------------------- launch
extern "C" void kernel_launch(void* const* d_in, const int* in_sizes, int n_in,
                              void* d_out, int out_size, void* d_ws, size_t ws_size,
                              hipStream_t stream)
{
    const float* x   = (const float*)d_in[0];
    const int*   ei  = (const int*)d_in[1];
    const float* pos = (const float*)d_in[2];

    const float* W[27];
    for (int i = 0; i < 27; i++) W[i] = (const float*)d_in[3 + i];
    // per conv c (0-based): w0=W[9c+0] b0=+1 w1=+2 b1=+3 w2=+4 b2=+5 wl=+6 bl=+7 bias=+8

    float* ws    = (float*)d_ws;
    float4* feat = (float4*)ws;                         // N_EDGES*4 floats
    float* xcat  = ws + (size_t)N_EDGES * 4;            // N*32
    float* acc1  = xcat + (size_t)N_NODES * 32;         // N*8
    float* acc2  = acc1 + (size_t)N_NODES * 8;          // N*8
    float* acc3  = acc2 + (size_t)N_NODES * 8;          // N*16
    float* P1    = acc3 + (size_t)N_NODES * 16;         // 1536 each
    float* P2    = P1 + 1536;
    float* P3    = P2 + 1536;
    float* tb    = P3 + 1536;                           // ETOT*16
    float* blxb  = tb + (size_t)ETOT * 16;              // ETOT
    float* out   = (float*)d_out;

    hipMemsetAsync(acc1, 0, (size_t)N_NODES * 32 * sizeof(float), stream);

    dim3 blk(256);
    dim3 gpre(2500);
    dim3 ge((ETOT + 255) / 256);
    dim3 gx((N_NODES * 16 + 255) / 256);
    dim3 g8((N_NODES * 8 + 255) / 256);
    dim3 gc8(N_EDGES / 8);    // conv OUT=8: E/2 waves -> E/8 blocks
    dim3 gc16(N_EDGES / 4);   // conv OUT=16: E waves -> E/4 blocks

    prep_conv_kernel<8> <<<1, blk, 0, stream>>>(W[0],  W[1],  W[2],  W[3],  W[4],  W[5],  P1);
    prep_conv_kernel<8> <<<1, blk, 0, stream>>>(W[9],  W[10], W[11], W[12], W[13], W[14], P2);
    prep_conv_kernel<16><<<1, blk, 0, stream>>>(W[18], W[19], W[20], W[21], W[22], W[23], P3);

    fused_pre_kernel<<<gpre, blk, 0, stream>>>(ei, pos, x, feat, xcat);

    tbuf_kernel<16><<<ge, blk, 0, stream>>>(ei, xcat, W[6], W[7], (float4*)tb, blxb);
    conv_mfma_kernel<8><<<gc8, blk, 0, stream>>>(ei, feat, P1, tb, blxb, acc1);
    finish_mid_kernel<8><<<g8, blk, 0, stream>>>(acc1, W[8], P1 + 1152, tb, blxb, xcat, 16);

    tbuf_kernel<24><<<ge, blk, 0, stream>>>(ei, xcat, W[15], W[16], (float4*)tb, blxb);
    conv_mfma_kernel<8><<<gc8, blk, 0, stream>>>(ei, feat, P2, tb, blxb, acc2);
    finish_mid_kernel<8><<<g8, blk, 0, stream>>>(acc2, W[17], P2 + 1152, tb, blxb, xcat, 24);

    tbuf_kernel<32><<<ge, blk, 0, stream>>>(ei, xcat, W[24], W[25], (float4*)tb, blxb);
    conv_mfma_kernel<16><<<gc16, blk, 0, stream>>>(ei, feat, P3, tb, blxb, acc3);
    finish_out_kernel<<<gx, blk, 0, stream>>>(acc3, W[26], P3 + 1152, tb, blxb, x, out);
}

// Round 7
// 247.344 us; speedup vs baseline: 1.3974x; 1.3974x over previous
//
#include <hip/hip_runtime.h>
#include <math.h>

#define N_NODES 20000
#define N_EDGES 320000
#define ETOT (N_EDGES + N_NODES)
#define HID 16
#define OMEGA 100.0f
#define BETA 0.2f

typedef float  f32x4 __attribute__((ext_vector_type(4)));
typedef short  s16x8 __attribute__((ext_vector_type(8)));

__device__ __forceinline__ float sinrev(float x) { return __builtin_amdgcn_sinf(x); }
__device__ __forceinline__ float fract_f(float x) { return __builtin_amdgcn_fractf(x); }

__device__ __forceinline__ float selu_f(float v) {
    const float a  = 1.6732632423543772f;
    const float sc = 1.0507009873554805f;
    return sc * (v > 0.f ? v : a * expm1f(v));
}

__device__ __forceinline__ f32x4 mfma16(s16x8 a, s16x8 b, f32x4 c) {
    return __builtin_amdgcn_mfma_f32_16x16x32_bf16(a, b, c, 0, 0, 0);
}

__device__ __forceinline__ unsigned pk_hi(float a, float b) {
    return (__float_as_uint(b) & 0xFFFF0000u) | (__float_as_uint(a) >> 16);
}

// B fragments: hi duplicated in k=[0..3],[4..7]; lo likewise (pairs with A=[wh|wl])
__device__ __forceinline__ void pack_b(const float* h, s16x8& Bh, s16x8& Bl) {
    union { s16x8 s; unsigned u[4]; } H, L;
    unsigned u0 = pk_hi(h[0], h[1]);
    unsigned u1 = pk_hi(h[2], h[3]);
    H.u[0] = u0; H.u[1] = u1; H.u[2] = u0; H.u[3] = u1;
    float r0 = h[0] - __uint_as_float(__float_as_uint(h[0]) & 0xFFFF0000u);
    float r1 = h[1] - __uint_as_float(__float_as_uint(h[1]) & 0xFFFF0000u);
    float r2 = h[2] - __uint_as_float(__float_as_uint(h[2]) & 0xFFFF0000u);
    float r3 = h[3] - __uint_as_float(__float_as_uint(h[3]) & 0xFFFF0000u);
    unsigned v0 = pk_hi(r0, r1);
    unsigned v1 = pk_hi(r2, r3);
    L.u[0] = v0; L.u[1] = v1; L.u[2] = v0; L.u[3] = v1;
    Bh = H.s; Bl = L.s;
}

// ---------------------------------------------------------------- per-conv prep
// P layout (floats): [0:64) w0 rows {x,y,z,c} prescaled; [64:80) s*b0;
// [80:96) s*b1; [96:112) s*b2; [128:384) w1 A-frag uint4[64] (e0-3 hi, e4-7 lo);
// [384:640) w2 A-frag; [640:640+OUT*16) h2v
template<int OUT>
__global__ __launch_bounds__(256) void prep_conv_kernel(
    const float* __restrict__ w0, const float* __restrict__ b0,
    const float* __restrict__ w1, const float* __restrict__ b1,
    const float* __restrict__ w2, const float* __restrict__ b2,
    float* __restrict__ P)
{
    __shared__ float w0s[64], b0s[16], sw1s[256], b1s[16], sw2s[256], b2s[16];
    int t = threadIdx.x;
    const float s = OMEGA * 0.15915494309189535f;  // omega/(2*pi)
    if (t < 64)  w0s[t] = s * w0[t];
    if (t < 16)  b0s[t] = s * b0[t];
    sw1s[t] = s * w1[t];
    sw2s[t] = s * w2[t];
    if (t >= 32 && t < 48) b1s[t - 32] = s * b1[t - 32];
    if (t >= 48 && t < 64) b2s[t - 48] = s * b2[t - 48];
    __syncthreads();

    if (t < 64)  P[t] = w0s[t];
    else if (t < 80)  P[t] = b0s[t - 64];
    else if (t < 96)  P[t] = b1s[t - 80];
    else if (t < 112) P[t] = b2s[t - 96];

    // A-fragments: lane holds row g=lane&15, k=(lane>>4)*8+e; e0-3 = hi(W[g][4q+e]),
    // e4-7 = lo(W[g][4q+e-4])
    if (t < 128) {
        int lane = t & 63;
        const float* W = (t < 64) ? sw1s : sw2s;
        float* dst = P + ((t < 64) ? 128 : 384);
        int g = lane & 15, q = lane >> 4;
        float w[4], r[4];
#pragma unroll
        for (int j = 0; j < 4; j++) {
            w[j] = W[g * 16 + 4 * q + j];
            r[j] = w[j] - __uint_as_float(__float_as_uint(w[j]) & 0xFFFF0000u);
        }
        ((uint4*)dst)[lane] = make_uint4(pk_hi(w[0], w[1]), pk_hi(w[2], w[3]),
                                         pk_hi(r[0], r[1]), pk_hi(r[2], r[3]));
    }

    // self-loop h2 chain (feat = 0): depends only on channel o
    if (t < OUT) {
        float oc = (float)t;
        float h0[HID], h1[HID];
#pragma unroll
        for (int h = 0; h < HID; h++)
            h0[h] = sinrev(fract_f(fmaf(oc, w0s[h * 4 + 3], b0s[h])));
#pragma unroll
        for (int g = 0; g < HID; g++) {
            float sa = b1s[g];
#pragma unroll
            for (int h = 0; h < HID; h++) sa += h0[h] * sw1s[g * HID + h];
            h1[g] = sinrev(sa);
        }
#pragma unroll
        for (int g = 0; g < HID; g++) {
            float sa = b2s[g];
#pragma unroll
            for (int h = 0; h < HID; h++) sa += h1[h] * sw2s[g * HID + h];
            P[640 + t * HID + g] = sinrev(sa);
        }
    }
}

// ---------------------------------------------------------------- edge feats + x copy (fused)
__global__ __launch_bounds__(256) void fused_pre_kernel(
    const int* __restrict__ ei, const float* __restrict__ pos,
    const float* __restrict__ x,
    float4* __restrict__ feat, float* __restrict__ xcat)
{
    if (blockIdx.x < 1250) {
        int e = blockIdx.x * 256 + threadIdx.x;
        if (e >= N_EDGES) return;
        int s = ei[e], d = ei[N_EDGES + e];
        float rx = pos[d * 3 + 0] - pos[s * 3 + 0];
        float ry = pos[d * 3 + 1] - pos[s * 3 + 1];
        float rz = pos[d * 3 + 2] - pos[s * 3 + 2];
        float sq = rx * rx + ry * ry + rz * rz;
        float4 f = make_float4(0.f, 0.f, 0.f, 0.f);
        if (sq > 0.f) {
            float rho = sqrtf(sq);
            float th  = atan2f(ry, rx);
            float ph  = asinf(fminf(fmaxf(rz / rho, -1.f), 1.f));
            const float inv_pi = 0.31830988618379067f;
            f = make_float4(rho, th * inv_pi, ph * inv_pi, 0.f);
        }
        feat[e] = f;
    } else {
        int i = (blockIdx.x - 1250) * 256 + threadIdx.x;
        if (i >= N_NODES * 16) return;
        int n = i >> 4, c = i & 15;
        xcat[n * 32 + c] = x[i];
    }
}

// ---------------------------------------------------------------- per-edge t
template<int IN>
__global__ __launch_bounds__(256) void tbuf_kernel(
    const int* __restrict__ ei, const float* __restrict__ xcat,
    const float* __restrict__ wl, const float* __restrict__ bl,
    float4* __restrict__ tbuf, float* __restrict__ blxb)
{
    int e = blockIdx.x * 256 + threadIdx.x;
    if (e >= ETOT) return;
    int s = (e < N_EDGES) ? ei[e] : e - N_EDGES;

    float t[HID];
#pragma unroll
    for (int h = 0; h < HID; h++) t[h] = 0.f;
    float blx = 0.f;
    const float4* xr = (const float4*)(xcat + s * 32);
#pragma unroll
    for (int i4 = 0; i4 < IN / 4; i4++) {
        float4 xv = xr[i4];
        blx += bl[i4 * 4 + 0] * xv.x + bl[i4 * 4 + 1] * xv.y
             + bl[i4 * 4 + 2] * xv.z + bl[i4 * 4 + 3] * xv.w;
#pragma unroll
        for (int h = 0; h < HID; h++) {
            t[h] += wl[(i4 * 4 + 0) * HID + h] * xv.x
                  + wl[(i4 * 4 + 1) * HID + h] * xv.y
                  + wl[(i4 * 4 + 2) * HID + h] * xv.z
                  + wl[(i4 * 4 + 3) * HID + h] * xv.w;
        }
    }
#pragma unroll
    for (int q = 0; q < 4; q++)
        tbuf[(size_t)e * 4 + q] = make_float4(t[q*4+0], t[q*4+1], t[q*4+2], t[q*4+3]);
    blxb[e] = blx;
}

// ---------------------------------------------------------------- conv via MFMA v2
// one MFMA set = 16 (edge, channel) items; a wave runs 2 independent sets.
// A = [w_hi | w_lo] along k; B = [b_hi|b_hi] then [b_lo|b_lo]: 2 MFMAs = exact product.
template<int OUT>
__device__ __forceinline__ void conv_set(
    int e, int lane, int q,
    const int* __restrict__ ei, const float4* __restrict__ feat,
    const float4* __restrict__ w0r, f32x4 b0q, f32x4 c1, f32x4 c2,
    s16x8 A1, s16x8 A2,
    const float* __restrict__ tb, const float* __restrict__ blxb,
    float& mOut, int& dOut, float& bxOut)
{
    int item = lane & 15;
    int o = item & (OUT - 1);
    int d = ei[N_EDGES + e];
    float4 f = feat[e];
    float oc = (float)o;

    // layer 1: this lane's 4 h-values (rows 4q+j)
    float h0[4];
#pragma unroll
    for (int j = 0; j < 4; j++) {
        float4 w = w0r[4 * q + j];
        float ph = b0q[j] + f.x * w.x + f.y * w.y + f.z * w.z + oc * w.w;
        h0[j] = sinrev(fract_f(ph));
    }
    s16x8 Bh, Bl;
    pack_b(h0, Bh, Bl);

    // layer 2: 2 MFMAs (hi+lo)
    f32x4 D = c1;
    D = mfma16(A1, Bh, D);
    D = mfma16(A1, Bl, D);
    float h1[4];
#pragma unroll
    for (int j = 0; j < 4; j++) h1[j] = sinrev(D[j]);
    pack_b(h1, Bh, Bl);

    // layer 3: 2 MFMAs
    f32x4 D2 = c2;
    D2 = mfma16(A2, Bh, D2);
    D2 = mfma16(A2, Bl, D2);

    // dot with t over this lane's rows, butterfly over quadrants
    f32x4 tv = *(const f32x4*)(tb + (size_t)e * 16 + 4 * q);
    float m = sinrev(D2[0]) * tv[0] + sinrev(D2[1]) * tv[1]
            + sinrev(D2[2]) * tv[2] + sinrev(D2[3]) * tv[3];
    m += __shfl_xor(m, 16);
    m += __shfl_xor(m, 32);
    mOut = m; dOut = d * OUT + o; bxOut = blxb[e];
}

template<int OUT>
__global__ __launch_bounds__(256) void conv_mfma2_kernel(
    const int* __restrict__ ei, const float4* __restrict__ feat,
    const float* __restrict__ P,
    const float* __restrict__ tb, const float* __restrict__ blxb,
    float* __restrict__ acc)
{
    constexpr int EPS = 16 / OUT;     // edges per set (1 or 2)
    int wid  = (blockIdx.x * 256 + threadIdx.x) >> 6;
    int lane = threadIdx.x & 63;
    int item = lane & 15, q = lane >> 4;
    int ebase = wid * 2 * EPS;
    int esub  = (EPS == 2) ? (item >> 3) : 0;

    union { uint4 v; s16x8 s; } A1u, A2u;
    A1u.v = ((const uint4*)(P + 128))[lane];
    A2u.v = ((const uint4*)(P + 384))[lane];
    const float4* w0r = (const float4*)P;
    f32x4 b0q = *(const f32x4*)(P + 64 + 4 * q);
    f32x4 c1  = *(const f32x4*)(P + 80 + 4 * q);
    f32x4 c2  = *(const f32x4*)(P + 96 + 4 * q);

    float m0, m1, bx0, bx1;
    int di0, di1;
    conv_set<OUT>(ebase + esub,       lane, q, ei, feat, w0r, b0q, c1, c2,
                  A1u.s, A2u.s, tb, blxb, m0, di0, bx0);
    conv_set<OUT>(ebase + EPS + esub, lane, q, ei, feat, w0r, b0q, c1, c2,
                  A1u.s, A2u.s, tb, blxb, m1, di1, bx1);

    if (lane < 32) {
        float mv = (lane & 16) ? m1  : m0;
        int   dv = (lane & 16) ? di1 : di0;
        float bv = (lane & 16) ? bx1 : bx0;
        atomicAdd(&acc[dv], mv + bv);
    }
}

// ---------------------------------------------------------------- finishers (+ self-loop term)
template<int OUT>
__global__ __launch_bounds__(256) void finish_mid_kernel(
    const float* __restrict__ acc, const float* __restrict__ bias,
    const float* __restrict__ h2v,
    const float* __restrict__ tb, const float* __restrict__ blxb,
    float* __restrict__ xcat, int coloff)
{
    int i = blockIdx.x * 256 + threadIdx.x;
    if (i >= N_NODES * OUT) return;
    int n = i / OUT, o = i % OUT;
    const float* tr = tb + (size_t)(N_EDGES + n) * 16;
    float m = blxb[N_EDGES + n];
#pragma unroll
    for (int h = 0; h < HID; h++) m += h2v[o * HID + h] * tr[h];
    xcat[n * 32 + coloff + o] = selu_f(acc[i] + bias[o] + m);
}

__global__ __launch_bounds__(256) void finish_out_kernel(
    const float* __restrict__ acc, const float* __restrict__ bias,
    const float* __restrict__ h2v,
    const float* __restrict__ tb, const float* __restrict__ blxb,
    const float* __restrict__ x, float* __restrict__ out)
{
    int i = blockIdx.x * 256 + threadIdx.x;
    if (i >= N_NODES * 16) return;
    int n = i >> 4, c = i & 15;
    const float* tr = tb + (size_t)(N_EDGES + n) * 16;
    float m = blxb[N_EDGES + n];
#pragma unroll
    for (int h = 0; h < HID; h++) m += h2v[c * HID + h] * tr[h];
    out[i] = x[i] + BETA * selu_f(acc[i] + bias[c] + m);
}

// ---------------------------------------------------------------- launch
extern "C" void kernel_launch(void* const* d_in, const int* in_sizes, int n_in,
                              void* d_out, int out_size, void* d_ws, size_t ws_size,
                              hipStream_t stream)
{
    const float* x   = (const float*)d_in[0];
    const int*   ei  = (const int*)d_in[1];
    const float* pos = (const float*)d_in[2];

    const float* W[27];
    for (int i = 0; i < 27; i++) W[i] = (const float*)d_in[3 + i];
    // per conv c (0-based): w0=W[9c+0] b0=+1 w1=+2 b1=+3 w2=+4 b2=+5 wl=+6 bl=+7 bias=+8

    float* ws    = (float*)d_ws;
    float4* feat = (float4*)ws;                         // N_EDGES*4 floats
    float* xcat  = ws + (size_t)N_EDGES * 4;            // N*32
    float* acc1  = xcat + (size_t)N_NODES * 32;         // N*8
    float* acc2  = acc1 + (size_t)N_NODES * 8;          // N*8
    float* acc3  = acc2 + (size_t)N_NODES * 8;          // N*16
    float* P1    = acc3 + (size_t)N_NODES * 16;         // 1024 each
    float* P2    = P1 + 1024;
    float* P3    = P2 + 1024;
    float* tb    = P3 + 1024;                           // ETOT*16
    float* blxb  = tb + (size_t)ETOT * 16;              // ETOT
    float* out   = (float*)d_out;

    hipMemsetAsync(acc1, 0, (size_t)N_NODES * 32 * sizeof(float), stream);

    dim3 blk(256);
    dim3 gpre(2500);
    dim3 ge((ETOT + 255) / 256);
    dim3 gx((N_NODES * 16 + 255) / 256);
    dim3 g8((N_NODES * 8 + 255) / 256);
    dim3 gc8(N_EDGES / 16);   // OUT=8: E/4 waves, 4 waves/block
    dim3 gc16(N_EDGES / 8);   // OUT=16: E/2 waves, 4 waves/block

    prep_conv_kernel<8> <<<1, blk, 0, stream>>>(W[0],  W[1],  W[2],  W[3],  W[4],  W[5],  P1);
    prep_conv_kernel<8> <<<1, blk, 0, stream>>>(W[9],  W[10], W[11], W[12], W[13], W[14], P2);
    prep_conv_kernel<16><<<1, blk, 0, stream>>>(W[18], W[19], W[20], W[21], W[22], W[23], P3);

    fused_pre_kernel<<<gpre, blk, 0, stream>>>(ei, pos, x, feat, xcat);

    tbuf_kernel<16><<<ge, blk, 0, stream>>>(ei, xcat, W[6], W[7], (float4*)tb, blxb);
    conv_mfma2_kernel<8><<<gc8, blk, 0, stream>>>(ei, feat, P1, tb, blxb, acc1);
    finish_mid_kernel<8><<<g8, blk, 0, stream>>>(acc1, W[8], P1 + 640, tb, blxb, xcat, 16);

    tbuf_kernel<24><<<ge, blk, 0, stream>>>(ei, xcat, W[15], W[16], (float4*)tb, blxb);
    conv_mfma2_kernel<8><<<gc8, blk, 0, stream>>>(ei, feat, P2, tb, blxb, acc2);
    finish_mid_kernel<8><<<g8, blk, 0, stream>>>(acc2, W[17], P2 + 640, tb, blxb, xcat, 24);

    tbuf_kernel<32><<<ge, blk, 0, stream>>>(ei, xcat, W[24], W[25], (float4*)tb, blxb);
    conv_mfma2_kernel<16><<<gc16, blk, 0, stream>>>(ei, feat, P3, tb, blxb, acc3);
    finish_out_kernel<<<gx, blk, 0, stream>>>(acc3, W[26], P3 + 640, tb, blxb, x, out);
}